// Round 16
// baseline (108.762 us; speedup 1.0000x reference)
//
#include <hip/hip_runtime.h>

// Maj3: out[b,o,h,w] = sum_{kh,c} sign( sum_{kw} x[b,c,h+kh-1,w+kw-1] * W[o,kw,kh,c] )
// x: (4,64,56,56) f32; W: (64,3,3,64) f32; out: (4,64,56,56) f32.
// Bit-exactness vs numpy required (threshold 1.36, integer output): contract(off),
// reference mul/add order per sign. Padded rows staged as 0.0 -> sums are +-0;
// the (s < 0) predicate counts neither, and base=nvalid*64 excludes them.
//
// R16: R15 (lane=channel, ballot sign-count) rebalanced. R15's 896 blocks =
// 3.5/CU -> 4-round ceiling (~14% idle tail); per-pixel overhead amortized
// over only 4 oo. Now: OG=8 (72 weight VGPRs/wave, loaded once), PIX=14,
// 4-wave 256-thr blocks, grid 224x4x2 = 1792 = exactly 7 blocks/CU. Slab rows
// 16 taps (pow2 staging math), stride 17 (odd -> 2 lanes/bank = free).

#define Cn 64
#define Hn 56
#define Wn 56
#define On 64
#define OG 8        // output channels per wave
#define PIX 14      // pixels per wave (quarter row)
#define SLABW 16    // staged taps per row: w0-1 .. w0+14 (pow2)
#define SLABP 17    // padded stride (odd -> bank-conflict-free column reads)

// v_writelane_b32: write wave-uniform `val` into lane `LANE` of `dst`.
// (No writelane builtin on this toolchain — inline asm, non-volatile so the
// scheduler may move it freely; value-tied via "+v".)
#define WRITELANE(dst, val, LANE)                                             \
    asm("v_writelane_b32 %0, %1, " #LANE                                      \
        : "+v"(dst) : "s"(val))

__global__ __launch_bounds__(256, 4)
void maj3_kernel(const float* __restrict__ x,
                 const float* __restrict__ wt,
                 float* __restrict__ out)
{
#pragma clang fp contract(off)
    __shared__ float slab[3][Cn][SLABP];

    const int lane  = threadIdx.x & 63;   // = channel c
    const int wave  = __builtin_amdgcn_readfirstlane((int)(threadIdx.x >> 6)); // 0..3
    const int bh    = blockIdx.x;         // 0..223
    const int b     = bh / Hn;
    const int h     = bh - b * Hn;
    const int w0    = blockIdx.y * PIX;   // 0,14,28,42
    const int obase = blockIdx.z * 32 + wave * OG;   // this wave's o range

    // Stage x[b, :, h-1..h+1, w0-1..w0+14] into slab; pads (rows and cols)
    // staged as exact 0.0f. 3072 elements over 256 threads, once per block.
    const float* xb = x + b * (Cn * Hn * Wn);
    for (int i = threadIdx.x; i < 3 * Cn * SLABW; i += 256) {
        const int ws  = i & (SLABW - 1);
        const int t   = i >> 4;
        const int c   = t & (Cn - 1);
        const int r   = t >> 6;
        const int row = h + r - 1;
        const int w   = w0 - 1 + ws;
        float v = 0.0f;
        if (row >= 0 && row < Hn && (unsigned)w < (unsigned)Wn)
            v = xb[(c * Hn + row) * Wn + w];
        slab[r][c][ws] = v;
    }

    // This wave's weights, lane = c: W[o,kw,kh,c] = wt[((o*3+kw)*3+kh)*64+c].
    // 72 coalesced 256B loads, once; lives in 72 VGPRs for the whole kernel.
    float wreg[OG][3][3];
    #pragma unroll
    for (int oo = 0; oo < OG; ++oo)
        #pragma unroll
        for (int kw = 0; kw < 3; ++kw)
            #pragma unroll
            for (int kh = 0; kh < 3; ++kh)
                wreg[oo][kh][kw] = wt[(((obase + oo) * 3 + kw) * 3 + kh) * Cn + lane];

    __syncthreads();

    int vcnt[OG];                         // lane p holds neg-count for pixel p
    #pragma unroll
    for (int oo = 0; oo < OG; ++oo) vcnt[oo] = 0;

    // Sliding 3-tap windows, one per kh row.
    float xl[3], xm[3];
    #pragma unroll
    for (int r = 0; r < 3; ++r) {
        xl[r] = slab[r][lane][0];
        xm[r] = slab[r][lane][1];
    }

#define PBODY(P)                                                              \
    do {                                                                      \
        float xr[3];                                                          \
        _Pragma("unroll")                                                     \
        for (int r = 0; r < 3; ++r) xr[r] = slab[r][lane][(P) + 2];           \
        _Pragma("unroll")                                                     \
        for (int oo = 0; oo < OG; ++oo) {                                     \
            int cnt = 0;                                                      \
            _Pragma("unroll")                                                 \
            for (int r = 0; r < 3; ++r) {                                     \
                const float s = (xl[r] * wreg[oo][r][0] +                     \
                                 xm[r] * wreg[oo][r][1])                      \
                              + xr[r] * wreg[oo][r][2];                       \
                cnt += (int)__popcll(__ballot(s < 0.0f));                     \
            }                                                                 \
            const int cs = __builtin_amdgcn_readfirstlane(cnt);              \
            WRITELANE(vcnt[oo], cs, P);                                       \
        }                                                                     \
        _Pragma("unroll")                                                     \
        for (int r = 0; r < 3; ++r) { xl[r] = xm[r]; xm[r] = xr[r]; }         \
    } while (0)

    PBODY(0);  PBODY(1);  PBODY(2);  PBODY(3);  PBODY(4);  PBODY(5);
    PBODY(6);  PBODY(7);  PBODY(8);  PBODY(9);  PBODY(10); PBODY(11);
    PBODY(12); PBODY(13);

    // out = nvalid*64 - 2*negcount (padded rows excluded; their staged-zero
    // sums are +-0 -> (s<0) false -> never counted).
    const int nvalid = 3 - (h == 0) - (h == Hn - 1);
    const float base = (float)(nvalid * Cn);
    if (lane < PIX) {
        float* ob = out + ((b * On + obase) * Hn + h) * Wn + w0 + lane;
        #pragma unroll
        for (int oo = 0; oo < OG; ++oo)
            ob[oo * Hn * Wn] = base - 2.0f * (float)vcnt[oo];
    }
}

extern "C" void kernel_launch(void* const* d_in, const int* in_sizes, int n_in,
                              void* d_out, int out_size, void* d_ws, size_t ws_size,
                              hipStream_t stream) {
    const float* x  = (const float*)d_in[0];
    const float* wt = (const float*)d_in[1];
    float* o        = (float*)d_out;
    dim3 grid(224, 4, 2);   // (b,h) x w-quarter x o-half; 4 waves x (14px, 8o)
    maj3_kernel<<<grid, dim3(256), 0, stream>>>(x, wt, o);
}